// Round 1
// baseline (508.026 us; speedup 1.0000x reference)
//
#include <hip/hip_runtime.h>
#include <math.h>

#define N_NODES 100000
#define N_PART  5000
#define N_EDGES 1000000
#define D_NODE  128
#define D_PART  128
#define D_ATT   20
#define PB      6   // particles per block in fused GRU kernel

__device__ __forceinline__ float sigmoid_(float x) { return 1.f / (1.f + __expf(-x)); }
__device__ __forceinline__ float tanh_(float x)    { return 1.f - 2.f / (__expf(2.f * x) + 1.f); }

// ---------------------------------------------------------------------------
// K1: query = [ph|gr] @ q_W + q_b  (per particle), then
//     qk[p][j] = sum_a key_W[j][a] * query[p][a]   (fold key_W into query)
//     qoff[p]  = sum_a key_b[a]    * query[p][a]
// ---------------------------------------------------------------------------
__global__ __launch_bounds__(128) void query_qk_kernel(
    const float* __restrict__ ph, const float* __restrict__ gr,
    const float* __restrict__ qW, const float* __restrict__ qb,
    const float* __restrict__ keyW, const float* __restrict__ keyb,
    float* __restrict__ qk, float* __restrict__ qoff)
{
    int p = blockIdx.x;
    int t = threadIdx.x;
    __shared__ float s_in[256];
    __shared__ float s_q[D_ATT];

    s_in[t]       = ph[p * 128 + t];
    s_in[128 + t] = gr[p * 128 + t];
    __syncthreads();

    if (t < D_ATT) {
        float acc = qb[t];
        #pragma unroll 8
        for (int k = 0; k < 256; k++) acc += s_in[k] * qW[k * D_ATT + t];
        s_q[t] = acc;
    }
    __syncthreads();

    float acc = 0.f;
    #pragma unroll
    for (int a = 0; a < D_ATT; a++) acc += keyW[t * D_ATT + a] * s_q[a];
    qk[p * 128 + t] = acc;

    if (t == 0) {
        float o = 0.f;
        #pragma unroll
        for (int a = 0; a < D_ATT; a++) o += keyb[a] * s_q[a];
        qoff[p] = o;
    }
}

// ---------------------------------------------------------------------------
// K2a: histogram of dst
// ---------------------------------------------------------------------------
__global__ __launch_bounds__(256) void hist_kernel(
    const int* __restrict__ dst, int* __restrict__ counts)
{
    int e = blockIdx.x * 256 + threadIdx.x;
    if (e < N_EDGES) atomicAdd(&counts[dst[e]], 1);
}

// ---------------------------------------------------------------------------
// K2b: exclusive scan of counts[5000] -> offsets[5001], cursor[5000]
// ---------------------------------------------------------------------------
__global__ __launch_bounds__(256) void scan_kernel(
    const int* __restrict__ counts, int* __restrict__ offsets, int* __restrict__ cursor)
{
    __shared__ int ss[256];
    int t = threadIdx.x;
    const int CH = 20;   // 256*20 = 5120 >= 5000
    int beg = t * CH;
    int end = min(beg + CH, N_PART);
    int lsum = 0;
    for (int i = beg; i < end; i++) lsum += counts[i];
    ss[t] = lsum;
    __syncthreads();
    for (int off = 1; off < 256; off <<= 1) {
        int v = (t >= off) ? ss[t - off] : 0;
        __syncthreads();
        ss[t] += v;
        __syncthreads();
    }
    int base = ss[t] - lsum;   // exclusive prefix
    for (int i = beg; i < end; i++) {
        offsets[i] = base;
        cursor[i]  = base;
        base += counts[i];
    }
    if (t == 0) offsets[N_PART] = N_EDGES;
}

// ---------------------------------------------------------------------------
// K2c: scatter src into dst-sorted order
// ---------------------------------------------------------------------------
__global__ __launch_bounds__(256) void scatter_kernel(
    const int* __restrict__ src, const int* __restrict__ dst,
    int* __restrict__ cursor, int* __restrict__ ssrc)
{
    int e = blockIdx.x * 256 + threadIdx.x;
    if (e < N_EDGES) {
        int d = dst[e];
        int pos = atomicAdd(&cursor[d], 1);
        ssrc[pos] = src[e];
    }
}

// ---------------------------------------------------------------------------
// K3: per-dst edge accumulation.
//   att_e = (nodes[s] . qk[p] + qoff[p]) * norm
//   agg[p]     += att_e * nodes[s]
//   att_sum[p] += att_e
// one block per particle, wave per edge (2 components per lane).
// ---------------------------------------------------------------------------
__global__ __launch_bounds__(256) void edge_agg_kernel(
    const float* __restrict__ nodes, const float* __restrict__ qk,
    const float* __restrict__ qoff,
    const int* __restrict__ offsets, const int* __restrict__ ssrc,
    float* __restrict__ agg, float* __restrict__ att_sum)
{
    const float norm = 0.22360679774997896f;  // 1/sqrt(20)
    int p = blockIdx.x;
    int lane = threadIdx.x & 63;
    int wave = threadIdx.x >> 6;

    const float2 q = *(const float2*)(qk + (size_t)p * 128 + 2 * lane);
    float qo = qoff[p];
    int beg = offsets[p], end = offsets[p + 1];

    float a0 = 0.f, a1 = 0.f, asum = 0.f;
    for (int i = beg + wave; i < end; i += 4) {
        int s = ssrc[i];
        const float2 x = *(const float2*)(nodes + (size_t)s * 128 + 2 * lane);
        float d = x.x * q.x + x.y * q.y;
        #pragma unroll
        for (int off = 32; off >= 1; off >>= 1) d += __shfl_xor(d, off, 64);
        float att = (d + qo) * norm;
        a0 += att * x.x;
        a1 += att * x.y;
        asum += att;
    }

    __shared__ float s_acc[4][128];
    __shared__ float s_as[4];
    s_acc[wave][2 * lane]     = a0;
    s_acc[wave][2 * lane + 1] = a1;
    if (lane == 0) s_as[wave] = asum;
    __syncthreads();

    if (threadIdx.x < 128) {
        int j = threadIdx.x;
        float v = s_acc[0][j] + s_acc[1][j] + s_acc[2][j] + s_acc[3][j];
        agg[(size_t)p * 128 + j] = v;
        if (j == 0) att_sum[p] = s_as[0] + s_as[1] + s_as[2] + s_as[3];
    }
}

// ---------------------------------------------------------------------------
// K4: fused  ws = agg @ val_W + att_sum*val_b ;  GRU ; LayerNorm ; MLP ; +res
// 6 particles per block, 384 threads (6 waves).
// ---------------------------------------------------------------------------
__global__ __launch_bounds__(384) void gru_fused_kernel(
    const float* __restrict__ agg, const float* __restrict__ att_sum,
    const float* __restrict__ ph,
    const float* __restrict__ valW, const float* __restrict__ valb,
    const float* __restrict__ Wih, const float* __restrict__ Whh,
    const float* __restrict__ bih, const float* __restrict__ bhh,
    const float* __restrict__ lng, const float* __restrict__ lnb,
    const float* __restrict__ W1, const float* __restrict__ b1,
    const float* __restrict__ W2, const float* __restrict__ b2,
    float* __restrict__ out)
{
    __shared__ float s_agg[PB][128];
    __shared__ float s_h[PB][128];
    __shared__ float s_ws[PB][128];
    __shared__ float s_gi[PB][384];
    __shared__ float s_gh[PB][384];
    __shared__ float s_ln[PB][128];
    __shared__ float s_a[PB][64];

    int t = threadIdx.x;
    int pbase = blockIdx.x * PB;

    // load agg + original hidden rows (clamped for tail block)
    for (int job = t; job < PB * 128; job += 384) {
        int lp = job >> 7, j = job & 127;
        int p = min(pbase + lp, N_PART - 1);
        s_agg[lp][j] = agg[(size_t)p * 128 + j];
        s_h[lp][j]   = ph[(size_t)p * 128 + j];
    }
    __syncthreads();

    // ws = agg @ val_W + att_sum * val_b
    for (int job = t; job < PB * 128; job += 384) {
        int lp = job >> 7, j = job & 127;
        int p = min(pbase + lp, N_PART - 1);
        float acc = att_sum[p] * valb[j];
        #pragma unroll 8
        for (int k = 0; k < 128; k++) acc += s_agg[lp][k] * valW[k * 128 + j];
        s_ws[lp][j] = acc;
    }
    __syncthreads();

    // gi = ws @ Wih^T + bih ; gh = h @ Whh^T + bhh   (thread = gate row)
    {
        int r = t;  // 0..383
        float gi[PB], gh[PB];
        float bi = bih[r], bh = bhh[r];
        #pragma unroll
        for (int lp = 0; lp < PB; lp++) { gi[lp] = bi; gh[lp] = bh; }
        const float4* wi4 = (const float4*)(Wih + (size_t)r * 128);
        const float4* wh4 = (const float4*)(Whh + (size_t)r * 128);
        for (int kc = 0; kc < 32; kc++) {
            float4 wi = wi4[kc];
            float4 wh = wh4[kc];
            #pragma unroll
            for (int lp = 0; lp < PB; lp++) {
                float4 x = ((const float4*)s_ws[lp])[kc];
                float4 h = ((const float4*)s_h[lp])[kc];
                gi[lp] += wi.x * x.x + wi.y * x.y + wi.z * x.z + wi.w * x.w;
                gh[lp] += wh.x * h.x + wh.y * h.y + wh.z * h.z + wh.w * h.w;
            }
        }
        #pragma unroll
        for (int lp = 0; lp < PB; lp++) { s_gi[lp][r] = gi[lp]; s_gh[lp][r] = gh[lp]; }
    }
    __syncthreads();

    // gates + LayerNorm: wave w <-> local particle w
    int w = t >> 6, l = t & 63;
    int p = pbase + w;
    bool valid = (p < N_PART);
    int j0 = l, j1 = l + 64;

    float hn0, hn1;
    {
        float ir = s_gi[w][j0], iz = s_gi[w][128 + j0], inn = s_gi[w][256 + j0];
        float hr = s_gh[w][j0], hz = s_gh[w][128 + j0], hnn = s_gh[w][256 + j0];
        float r = sigmoid_(ir + hr), z = sigmoid_(iz + hz);
        float n = tanh_(inn + r * hnn);
        hn0 = (1.f - z) * n + z * s_h[w][j0];
    }
    {
        float ir = s_gi[w][j1], iz = s_gi[w][128 + j1], inn = s_gi[w][256 + j1];
        float hr = s_gh[w][j1], hz = s_gh[w][128 + j1], hnn = s_gh[w][256 + j1];
        float r = sigmoid_(ir + hr), z = sigmoid_(iz + hz);
        float n = tanh_(inn + r * hnn);
        hn1 = (1.f - z) * n + z * s_h[w][j1];
    }
    float sum = hn0 + hn1, sq = hn0 * hn0 + hn1 * hn1;
    #pragma unroll
    for (int off = 32; off >= 1; off >>= 1) {
        sum += __shfl_xor(sum, off, 64);
        sq  += __shfl_xor(sq, off, 64);
    }
    float mu = sum * (1.f / 128.f);
    float var = sq * (1.f / 128.f) - mu * mu;
    float rstd = rsqrtf(var + 1e-5f);
    s_ln[w][j0] = (hn0 - mu) * rstd * lng[j0] + lnb[j0];
    s_ln[w][j1] = (hn1 - mu) * rstd * lng[j1] + lnb[j1];
    __syncthreads();

    // MLP hidden (64): lane l -> a_l
    {
        float acc = b1[l];
        #pragma unroll 8
        for (int k = 0; k < 128; k++) acc += s_ln[w][k] * W1[k * 64 + l];
        s_a[w][l] = fmaxf(acc, 0.f);
    }
    __syncthreads();

    // MLP out (128) + residual
    {
        float o0 = b2[j0], o1 = b2[j1];
        #pragma unroll 8
        for (int u = 0; u < 64; u++) {
            float av = s_a[w][u];
            o0 += av * W2[u * 128 + j0];
            o1 += av * W2[u * 128 + j1];
        }
        if (valid) {
            out[(size_t)p * 128 + j0] = s_h[w][j0] + o0;
            out[(size_t)p * 128 + j1] = s_h[w][j1] + o1;
        }
    }
}

// ---------------------------------------------------------------------------
extern "C" void kernel_launch(void* const* d_in, const int* in_sizes, int n_in,
                              void* d_out, int out_size, void* d_ws, size_t ws_size,
                              hipStream_t stream) {
    const float* nodes = (const float*)d_in[0];
    const float* ph    = (const float*)d_in[1];
    const float* gr    = (const float*)d_in[2];
    const int*   src   = (const int*)d_in[3];
    const int*   dst   = (const int*)d_in[4];
    const float* keyW  = (const float*)d_in[5];
    const float* keyb  = (const float*)d_in[6];
    const float* valW  = (const float*)d_in[7];
    const float* valb  = (const float*)d_in[8];
    const float* qW    = (const float*)d_in[9];
    const float* qb    = (const float*)d_in[10];
    const float* Wih   = (const float*)d_in[11];
    const float* Whh   = (const float*)d_in[12];
    const float* bih   = (const float*)d_in[13];
    const float* bhh   = (const float*)d_in[14];
    const float* lng   = (const float*)d_in[15];
    const float* lnb   = (const float*)d_in[16];
    const float* W1    = (const float*)d_in[17];
    const float* b1    = (const float*)d_in[18];
    const float* W2    = (const float*)d_in[19];
    const float* b2    = (const float*)d_in[20];
    float* out = (float*)d_out;

    // workspace layout (floats/ints, 16B-aligned chunks)
    float* ws_f    = (float*)d_ws;
    float* qk      = ws_f;                    // 640,000
    float* qoff    = qk + 640000;             // 5,000
    float* agg     = qoff + 5008;             // 640,000
    float* att_sum = agg + 640000;            // 5,000
    int*   counts  = (int*)(att_sum + 5008);  // 5,000
    int*   offsets = counts + 5008;           // 5,001
    int*   cursor  = offsets + 5008;          // 5,000
    int*   ssrc    = cursor + 5008;           // 1,000,000

    hipMemsetAsync(counts, 0, N_PART * sizeof(int), stream);

    query_qk_kernel<<<N_PART, 128, 0, stream>>>(ph, gr, qW, qb, keyW, keyb, qk, qoff);
    hist_kernel<<<(N_EDGES + 255) / 256, 256, 0, stream>>>(dst, counts);
    scan_kernel<<<1, 256, 0, stream>>>(counts, offsets, cursor);
    scatter_kernel<<<(N_EDGES + 255) / 256, 256, 0, stream>>>(src, dst, cursor, ssrc);
    edge_agg_kernel<<<N_PART, 256, 0, stream>>>(nodes, qk, qoff, offsets, ssrc, agg, att_sum);
    gru_fused_kernel<<<(N_PART + PB - 1) / PB, 384, 0, stream>>>(
        agg, att_sum, ph, valW, valb, Wih, Whh, bih, bhh, lng, lnb, W1, b1, W2, b2, out);
}

// Round 2
// 365.740 us; speedup vs baseline: 1.3890x; 1.3890x over previous
//
#include <hip/hip_runtime.h>
#include <math.h>

#define N_NODES 100000
#define N_PART  5000
#define N_EDGES 1000000
#define D_NODE  128
#define D_PART  128
#define D_ATT   20
#define PB      6     // particles per block in fused GRU kernel
#define NBLK    128   // counting-sort blocks
#define EPB     ((N_EDGES + NBLK - 1) / NBLK)

__device__ __forceinline__ float sigmoid_(float x) { return 1.f / (1.f + __expf(-x)); }
__device__ __forceinline__ float tanh_(float x)    { return 1.f - 2.f / (__expf(2.f * x) + 1.f); }

// ---------------------------------------------------------------------------
// K1: query = [ph|gr] @ q_W + q_b  (per particle), then fold key_W / key_b:
//     qk[p][j] = sum_a key_W[j][a] * query[p][a]
//     qoff[p]  = sum_a key_b[a]    * query[p][a]
// ---------------------------------------------------------------------------
__global__ __launch_bounds__(128) void query_qk_kernel(
    const float* __restrict__ ph, const float* __restrict__ gr,
    const float* __restrict__ qW, const float* __restrict__ qb,
    const float* __restrict__ keyW, const float* __restrict__ keyb,
    float* __restrict__ qk, float* __restrict__ qoff)
{
    int p = blockIdx.x;
    int t = threadIdx.x;
    __shared__ float s_in[256];
    __shared__ float s_q[D_ATT];

    s_in[t]       = ph[p * 128 + t];
    s_in[128 + t] = gr[p * 128 + t];
    __syncthreads();

    if (t < D_ATT) {
        float acc = qb[t];
        #pragma unroll 8
        for (int k = 0; k < 256; k++) acc += s_in[k] * qW[k * D_ATT + t];
        s_q[t] = acc;
    }
    __syncthreads();

    float acc = 0.f;
    #pragma unroll
    for (int a = 0; a < D_ATT; a++) acc += keyW[t * D_ATT + a] * s_q[a];
    qk[p * 128 + t] = acc;

    if (t == 0) {
        float o = 0.f;
        #pragma unroll
        for (int a = 0; a < D_ATT; a++) o += keyb[a] * s_q[a];
        qoff[p] = o;
    }
}

// ---------------------------------------------------------------------------
// K2a: per-block LDS histogram of dst  ->  blockhist[b][i]
// ---------------------------------------------------------------------------
__global__ __launch_bounds__(256) void block_hist_kernel(
    const int* __restrict__ dst, int* __restrict__ blockhist)
{
    __shared__ int h[N_PART];
    int b = blockIdx.x;
    for (int i = threadIdx.x; i < N_PART; i += 256) h[i] = 0;
    __syncthreads();
    int beg = b * EPB, end = min(beg + EPB, N_EDGES);
    for (int e = beg + threadIdx.x; e < end; e += 256)
        atomicAdd(&h[dst[e]], 1);
    __syncthreads();
    for (int i = threadIdx.x; i < N_PART; i += 256)
        blockhist[(size_t)b * N_PART + i] = h[i];
}

// ---------------------------------------------------------------------------
// K2b: per-dst column scan over blocks (in place -> exclusive prefix),
//      totals[i] = column sum
// ---------------------------------------------------------------------------
__global__ __launch_bounds__(256) void colscan_kernel(
    int* __restrict__ blockhist, int* __restrict__ totals)
{
    int i = blockIdx.x * 256 + threadIdx.x;
    if (i >= N_PART) return;
    int run = 0;
    for (int b = 0; b < NBLK; b++) {
        size_t idx = (size_t)b * N_PART + i;
        int v = blockhist[idx];
        blockhist[idx] = run;
        run += v;
    }
    totals[i] = run;
}

// ---------------------------------------------------------------------------
// K2c: exclusive scan of totals[5000] -> offsets[5001]
// ---------------------------------------------------------------------------
__global__ __launch_bounds__(256) void scan_kernel(
    const int* __restrict__ totals, int* __restrict__ offsets)
{
    __shared__ int ss[256];
    int t = threadIdx.x;
    const int CH = 20;   // 256*20 = 5120 >= 5000
    int beg = t * CH;
    int end = min(beg + CH, N_PART);
    int lsum = 0;
    for (int i = beg; i < end; i++) lsum += totals[i];
    ss[t] = lsum;
    __syncthreads();
    for (int off = 1; off < 256; off <<= 1) {
        int v = (t >= off) ? ss[t - off] : 0;
        __syncthreads();
        ss[t] += v;
        __syncthreads();
    }
    int base = ss[t] - lsum;   // exclusive prefix
    for (int i = beg; i < end; i++) {
        offsets[i] = base;
        base += totals[i];
    }
    if (t == 0) offsets[N_PART] = N_EDGES;
}

// ---------------------------------------------------------------------------
// K2d: scatter src into dst-sorted order using per-block LDS cursors
// ---------------------------------------------------------------------------
__global__ __launch_bounds__(256) void scatter_sorted_kernel(
    const int* __restrict__ src, const int* __restrict__ dst,
    const int* __restrict__ offsets, const int* __restrict__ blockhist,
    int* __restrict__ ssrc)
{
    __shared__ int cur[N_PART];
    int b = blockIdx.x;
    for (int i = threadIdx.x; i < N_PART; i += 256)
        cur[i] = offsets[i] + blockhist[(size_t)b * N_PART + i];
    __syncthreads();
    int beg = b * EPB, end = min(beg + EPB, N_EDGES);
    for (int e = beg + threadIdx.x; e < end; e += 256) {
        int d = dst[e];
        int pos = atomicAdd(&cur[d], 1);
        ssrc[pos] = src[e];
    }
}

// ---------------------------------------------------------------------------
// K3: per-dst edge accumulation.
//   att_e = (nodes[s] . qk[p] + qoff[p]) * norm
//   agg[p] += att_e * nodes[s];  att_sum[p] += att_e
// One block per particle. Half-wave (32 lanes x float4) per edge; each wave
// processes edge-pairs; unrolled x2 -> 4 independent 16B gathers in flight.
// ---------------------------------------------------------------------------
__global__ __launch_bounds__(256) void edge_agg_kernel(
    const float* __restrict__ nodes, const float* __restrict__ qk,
    const float* __restrict__ qoff,
    const int* __restrict__ offsets, const int* __restrict__ ssrc,
    float* __restrict__ agg, float* __restrict__ att_sum)
{
    const float norm = 0.22360679774997896f;  // 1/sqrt(20)
    int p = blockIdx.x;
    int tid = threadIdx.x;
    int lane = tid & 63;
    int wave = tid >> 6;
    int half = lane >> 5;
    int colq = (lane & 31) * 4;

    const float4 q = *(const float4*)(qk + (size_t)p * 128 + colq);
    float qo = qoff[p];
    int beg = offsets[p], end = offsets[p + 1];
    int n = end - beg;
    int np = (n + 1) >> 1;   // number of edge pairs

    float4 a = {0.f, 0.f, 0.f, 0.f};
    float asum = 0.f;

    int pi = wave;
    // main loop: pairs pi and pi+4 (pair A always full here)
    for (; pi + 4 < np; pi += 8) {
        int eA = beg + 2 * pi;
        int eB = eA + 8;
        bool hasB1 = (eB + 1 < end);
        int sA0 = ssrc[eA];
        int sA1 = ssrc[eA + 1];
        int sB0 = ssrc[eB];
        int sB1 = hasB1 ? ssrc[eB + 1] : sB0;
        int sA = half ? sA1 : sA0;
        int sB = half ? sB1 : sB0;
        float4 xA = *(const float4*)(nodes + (size_t)sA * 128 + colq);
        float4 xB = *(const float4*)(nodes + (size_t)sB * 128 + colq);
        float dA = xA.x * q.x + xA.y * q.y + xA.z * q.z + xA.w * q.w;
        float dB = xB.x * q.x + xB.y * q.y + xB.z * q.z + xB.w * q.w;
        #pragma unroll
        for (int off = 1; off <= 16; off <<= 1) {
            dA += __shfl_xor(dA, off, 64);
            dB += __shfl_xor(dB, off, 64);
        }
        float attA = (dA + qo) * norm;
        float attB = (dB + qo) * norm;
        if (half && !hasB1) attB = 0.f;
        a.x += attA * xA.x; a.y += attA * xA.y; a.z += attA * xA.z; a.w += attA * xA.w;
        a.x += attB * xB.x; a.y += attB * xB.y; a.z += attB * xB.z; a.w += attB * xB.w;
        asum += attA + attB;
    }
    // tail: at most one pair left for this wave
    if (pi < np) {
        int e0 = beg + 2 * pi;
        bool has1 = (e0 + 1 < end);
        int s0 = ssrc[e0];
        int s1 = has1 ? ssrc[e0 + 1] : s0;
        int s = half ? s1 : s0;
        float4 x = *(const float4*)(nodes + (size_t)s * 128 + colq);
        float d = x.x * q.x + x.y * q.y + x.z * q.z + x.w * q.w;
        #pragma unroll
        for (int off = 1; off <= 16; off <<= 1) d += __shfl_xor(d, off, 64);
        float att = (d + qo) * norm;
        if (half && !has1) att = 0.f;
        a.x += att * x.x; a.y += att * x.y; a.z += att * x.z; a.w += att * x.w;
        asum += att;
    }

    // combine the two half-waves
    a.x += __shfl_xor(a.x, 32, 64);
    a.y += __shfl_xor(a.y, 32, 64);
    a.z += __shfl_xor(a.z, 32, 64);
    a.w += __shfl_xor(a.w, 32, 64);
    asum += __shfl_xor(asum, 32, 64);

    __shared__ float s_acc[4][128];
    __shared__ float s_as[4];
    if (lane < 32) {
        *(float4*)&s_acc[wave][colq] = a;
        if (lane == 0) s_as[wave] = asum;
    }
    __syncthreads();

    if (tid < 128) {
        float v = s_acc[0][tid] + s_acc[1][tid] + s_acc[2][tid] + s_acc[3][tid];
        agg[(size_t)p * 128 + tid] = v;
        if (tid == 0) att_sum[p] = s_as[0] + s_as[1] + s_as[2] + s_as[3];
    }
}

// ---------------------------------------------------------------------------
// K4: fused  ws = agg @ val_W + att_sum*val_b ;  GRU ; LayerNorm ; MLP ; +res
// ---------------------------------------------------------------------------
__global__ __launch_bounds__(384) void gru_fused_kernel(
    const float* __restrict__ agg, const float* __restrict__ att_sum,
    const float* __restrict__ ph,
    const float* __restrict__ valW, const float* __restrict__ valb,
    const float* __restrict__ Wih, const float* __restrict__ Whh,
    const float* __restrict__ bih, const float* __restrict__ bhh,
    const float* __restrict__ lng, const float* __restrict__ lnb,
    const float* __restrict__ W1, const float* __restrict__ b1,
    const float* __restrict__ W2, const float* __restrict__ b2,
    float* __restrict__ out)
{
    __shared__ float s_agg[PB][128];
    __shared__ float s_h[PB][128];
    __shared__ float s_ws[PB][128];
    __shared__ float s_gi[PB][384];
    __shared__ float s_gh[PB][384];
    __shared__ float s_ln[PB][128];
    __shared__ float s_a[PB][64];

    int t = threadIdx.x;
    int pbase = blockIdx.x * PB;

    for (int job = t; job < PB * 128; job += 384) {
        int lp = job >> 7, j = job & 127;
        int p = min(pbase + lp, N_PART - 1);
        s_agg[lp][j] = agg[(size_t)p * 128 + j];
        s_h[lp][j]   = ph[(size_t)p * 128 + j];
    }
    __syncthreads();

    for (int job = t; job < PB * 128; job += 384) {
        int lp = job >> 7, j = job & 127;
        int p = min(pbase + lp, N_PART - 1);
        float acc = att_sum[p] * valb[j];
        #pragma unroll 8
        for (int k = 0; k < 128; k++) acc += s_agg[lp][k] * valW[k * 128 + j];
        s_ws[lp][j] = acc;
    }
    __syncthreads();

    {
        int r = t;  // 0..383 gate row
        float gi[PB], gh[PB];
        float bi = bih[r], bh = bhh[r];
        #pragma unroll
        for (int lp = 0; lp < PB; lp++) { gi[lp] = bi; gh[lp] = bh; }
        const float4* wi4 = (const float4*)(Wih + (size_t)r * 128);
        const float4* wh4 = (const float4*)(Whh + (size_t)r * 128);
        for (int kc = 0; kc < 32; kc++) {
            float4 wi = wi4[kc];
            float4 wh = wh4[kc];
            #pragma unroll
            for (int lp = 0; lp < PB; lp++) {
                float4 x = ((const float4*)s_ws[lp])[kc];
                float4 h = ((const float4*)s_h[lp])[kc];
                gi[lp] += wi.x * x.x + wi.y * x.y + wi.z * x.z + wi.w * x.w;
                gh[lp] += wh.x * h.x + wh.y * h.y + wh.z * h.z + wh.w * h.w;
            }
        }
        #pragma unroll
        for (int lp = 0; lp < PB; lp++) { s_gi[lp][r] = gi[lp]; s_gh[lp][r] = gh[lp]; }
    }
    __syncthreads();

    int w = t >> 6, l = t & 63;
    int p = pbase + w;
    bool valid = (p < N_PART);
    int j0 = l, j1 = l + 64;

    float hn0, hn1;
    {
        float ir = s_gi[w][j0], iz = s_gi[w][128 + j0], inn = s_gi[w][256 + j0];
        float hr = s_gh[w][j0], hz = s_gh[w][128 + j0], hnn = s_gh[w][256 + j0];
        float r = sigmoid_(ir + hr), z = sigmoid_(iz + hz);
        float n = tanh_(inn + r * hnn);
        hn0 = (1.f - z) * n + z * s_h[w][j0];
    }
    {
        float ir = s_gi[w][j1], iz = s_gi[w][128 + j1], inn = s_gi[w][256 + j1];
        float hr = s_gh[w][j1], hz = s_gh[w][128 + j1], hnn = s_gh[w][256 + j1];
        float r = sigmoid_(ir + hr), z = sigmoid_(iz + hz);
        float n = tanh_(inn + r * hnn);
        hn1 = (1.f - z) * n + z * s_h[w][j1];
    }
    float sum = hn0 + hn1, sq = hn0 * hn0 + hn1 * hn1;
    #pragma unroll
    for (int off = 32; off >= 1; off >>= 1) {
        sum += __shfl_xor(sum, off, 64);
        sq  += __shfl_xor(sq, off, 64);
    }
    float mu = sum * (1.f / 128.f);
    float var = sq * (1.f / 128.f) - mu * mu;
    float rstd = rsqrtf(var + 1e-5f);
    s_ln[w][j0] = (hn0 - mu) * rstd * lng[j0] + lnb[j0];
    s_ln[w][j1] = (hn1 - mu) * rstd * lng[j1] + lnb[j1];
    __syncthreads();

    {
        float acc = b1[l];
        #pragma unroll 8
        for (int k = 0; k < 128; k++) acc += s_ln[w][k] * W1[k * 64 + l];
        s_a[w][l] = fmaxf(acc, 0.f);
    }
    __syncthreads();

    {
        float o0 = b2[j0], o1 = b2[j1];
        #pragma unroll 8
        for (int u = 0; u < 64; u++) {
            float av = s_a[w][u];
            o0 += av * W2[u * 128 + j0];
            o1 += av * W2[u * 128 + j1];
        }
        if (valid) {
            out[(size_t)p * 128 + j0] = s_h[w][j0] + o0;
            out[(size_t)p * 128 + j1] = s_h[w][j1] + o1;
        }
    }
}

// ---------------------------------------------------------------------------
extern "C" void kernel_launch(void* const* d_in, const int* in_sizes, int n_in,
                              void* d_out, int out_size, void* d_ws, size_t ws_size,
                              hipStream_t stream) {
    const float* nodes = (const float*)d_in[0];
    const float* ph    = (const float*)d_in[1];
    const float* gr    = (const float*)d_in[2];
    const int*   src   = (const int*)d_in[3];
    const int*   dst   = (const int*)d_in[4];
    const float* keyW  = (const float*)d_in[5];
    const float* keyb  = (const float*)d_in[6];
    const float* valW  = (const float*)d_in[7];
    const float* valb  = (const float*)d_in[8];
    const float* qW    = (const float*)d_in[9];
    const float* qb    = (const float*)d_in[10];
    const float* Wih   = (const float*)d_in[11];
    const float* Whh   = (const float*)d_in[12];
    const float* bih   = (const float*)d_in[13];
    const float* bhh   = (const float*)d_in[14];
    const float* lng   = (const float*)d_in[15];
    const float* lnb   = (const float*)d_in[16];
    const float* W1    = (const float*)d_in[17];
    const float* b1    = (const float*)d_in[18];
    const float* W2    = (const float*)d_in[19];
    const float* b2    = (const float*)d_in[20];
    float* out = (float*)d_out;

    // workspace layout
    float* ws_f      = (float*)d_ws;
    float* qk        = ws_f;                     // 640,000
    float* qoff      = qk + 640000;              // 5,008
    float* agg       = qoff + 5008;              // 640,000
    float* att_sum   = agg + 640000;             // 5,008
    int*   totals    = (int*)(att_sum + 5008);   // 5,008
    int*   offsets   = totals + 5008;            // 5,008
    int*   blockhist = offsets + 5008;           // NBLK*5000 = 640,000
    int*   ssrc      = blockhist + (size_t)NBLK * N_PART;  // 1,000,000

    query_qk_kernel<<<N_PART, 128, 0, stream>>>(ph, gr, qW, qb, keyW, keyb, qk, qoff);
    block_hist_kernel<<<NBLK, 256, 0, stream>>>(dst, blockhist);
    colscan_kernel<<<(N_PART + 255) / 256, 256, 0, stream>>>(blockhist, totals);
    scan_kernel<<<1, 256, 0, stream>>>(totals, offsets);
    scatter_sorted_kernel<<<NBLK, 256, 0, stream>>>(src, dst, offsets, blockhist, ssrc);
    edge_agg_kernel<<<N_PART, 256, 0, stream>>>(nodes, qk, qoff, offsets, ssrc, agg, att_sum);
    gru_fused_kernel<<<(N_PART + PB - 1) / PB, 384, 0, stream>>>(
        agg, att_sum, ph, valW, valb, Wih, Whh, bih, bhh, lng, lnb, W1, b1, W2, b2, out);
}

// Round 3
// 348.844 us; speedup vs baseline: 1.4563x; 1.0484x over previous
//
#include <hip/hip_runtime.h>
#include <math.h>

#define N_NODES 100000
#define N_PART  5000
#define N_EDGES 1000000
#define D_NODE  128
#define D_PART  128
#define D_ATT   20
#define TP      8     // particles per block in fused GRU kernel (5000 = 625*8)
#define NBLK    128   // counting-sort blocks
#define EPB     ((N_EDGES + NBLK - 1) / NBLK)

__device__ __forceinline__ float sigmoid_(float x) { return 1.f / (1.f + __expf(-x)); }
__device__ __forceinline__ float tanh_(float x)    { return 1.f - 2.f / (__expf(2.f * x) + 1.f); }

// ---------------------------------------------------------------------------
// K0: transpose Wih/Whh [384][128] -> [128][384] for coalesced K-loop loads
// ---------------------------------------------------------------------------
__global__ __launch_bounds__(256) void transpose_w_kernel(
    const float* __restrict__ Wih, const float* __restrict__ Whh,
    float* __restrict__ WihT, float* __restrict__ WhhT)
{
    int tid = blockIdx.x * 256 + threadIdx.x;
    if (tid < 384 * 128) {
        int j = tid >> 7, k = tid & 127;
        WihT[k * 384 + j] = Wih[tid];
        WhhT[k * 384 + j] = Whh[tid];
    }
}

// ---------------------------------------------------------------------------
// K1: query = [ph|gr] @ q_W + q_b, fold key_W/key_b:
//     qk[p][j] = sum_a key_W[j][a] * query[p][a];  qoff[p] = key_b . query[p]
// ---------------------------------------------------------------------------
__global__ __launch_bounds__(128) void query_qk_kernel(
    const float* __restrict__ ph, const float* __restrict__ gr,
    const float* __restrict__ qW, const float* __restrict__ qb,
    const float* __restrict__ keyW, const float* __restrict__ keyb,
    float* __restrict__ qk, float* __restrict__ qoff)
{
    int p = blockIdx.x;
    int t = threadIdx.x;
    __shared__ float s_in[256];
    __shared__ float s_q[D_ATT];

    s_in[t]       = ph[p * 128 + t];
    s_in[128 + t] = gr[p * 128 + t];
    __syncthreads();

    if (t < D_ATT) {
        float acc = qb[t];
        #pragma unroll 8
        for (int k = 0; k < 256; k++) acc += s_in[k] * qW[k * D_ATT + t];
        s_q[t] = acc;
    }
    __syncthreads();

    float acc = 0.f;
    #pragma unroll
    for (int a = 0; a < D_ATT; a++) acc += keyW[t * D_ATT + a] * s_q[a];
    qk[p * 128 + t] = acc;

    if (t == 0) {
        float o = 0.f;
        #pragma unroll
        for (int a = 0; a < D_ATT; a++) o += keyb[a] * s_q[a];
        qoff[p] = o;
    }
}

// ---------------------------------------------------------------------------
// K2a: per-block LDS histogram of dst
// ---------------------------------------------------------------------------
__global__ __launch_bounds__(256) void block_hist_kernel(
    const int* __restrict__ dst, int* __restrict__ blockhist)
{
    __shared__ int h[N_PART];
    int b = blockIdx.x;
    for (int i = threadIdx.x; i < N_PART; i += 256) h[i] = 0;
    __syncthreads();
    int beg = b * EPB, end = min(beg + EPB, N_EDGES);
    for (int e = beg + threadIdx.x; e < end; e += 256)
        atomicAdd(&h[dst[e]], 1);
    __syncthreads();
    for (int i = threadIdx.x; i < N_PART; i += 256)
        blockhist[(size_t)b * N_PART + i] = h[i];
}

// ---------------------------------------------------------------------------
// K2b: per-dst column scan over blocks
// ---------------------------------------------------------------------------
__global__ __launch_bounds__(256) void colscan_kernel(
    int* __restrict__ blockhist, int* __restrict__ totals)
{
    int i = blockIdx.x * 256 + threadIdx.x;
    if (i >= N_PART) return;
    int run = 0;
    for (int b = 0; b < NBLK; b++) {
        size_t idx = (size_t)b * N_PART + i;
        int v = blockhist[idx];
        blockhist[idx] = run;
        run += v;
    }
    totals[i] = run;
}

// ---------------------------------------------------------------------------
// K2c: exclusive scan of totals[5000] -> offsets[5001]
// ---------------------------------------------------------------------------
__global__ __launch_bounds__(256) void scan_kernel(
    const int* __restrict__ totals, int* __restrict__ offsets)
{
    __shared__ int ss[256];
    int t = threadIdx.x;
    const int CH = 20;
    int beg = t * CH;
    int end = min(beg + CH, N_PART);
    int lsum = 0;
    for (int i = beg; i < end; i++) lsum += totals[i];
    ss[t] = lsum;
    __syncthreads();
    for (int off = 1; off < 256; off <<= 1) {
        int v = (t >= off) ? ss[t - off] : 0;
        __syncthreads();
        ss[t] += v;
        __syncthreads();
    }
    int base = ss[t] - lsum;
    for (int i = beg; i < end; i++) {
        offsets[i] = base;
        base += totals[i];
    }
    if (t == 0) offsets[N_PART] = N_EDGES;
}

// ---------------------------------------------------------------------------
// K2d: scatter src into dst-sorted order using per-block LDS cursors
// ---------------------------------------------------------------------------
__global__ __launch_bounds__(256) void scatter_sorted_kernel(
    const int* __restrict__ src, const int* __restrict__ dst,
    const int* __restrict__ offsets, const int* __restrict__ blockhist,
    int* __restrict__ ssrc)
{
    __shared__ int cur[N_PART];
    int b = blockIdx.x;
    for (int i = threadIdx.x; i < N_PART; i += 256)
        cur[i] = offsets[i] + blockhist[(size_t)b * N_PART + i];
    __syncthreads();
    int beg = b * EPB, end = min(beg + EPB, N_EDGES);
    for (int e = beg + threadIdx.x; e < end; e += 256) {
        int d = dst[e];
        int pos = atomicAdd(&cur[d], 1);
        ssrc[pos] = src[e];
    }
}

// ---------------------------------------------------------------------------
// K3: per-dst edge accumulation (unchanged from R2)
// ---------------------------------------------------------------------------
__global__ __launch_bounds__(256) void edge_agg_kernel(
    const float* __restrict__ nodes, const float* __restrict__ qk,
    const float* __restrict__ qoff,
    const int* __restrict__ offsets, const int* __restrict__ ssrc,
    float* __restrict__ agg, float* __restrict__ att_sum)
{
    const float norm = 0.22360679774997896f;  // 1/sqrt(20)
    int p = blockIdx.x;
    int tid = threadIdx.x;
    int lane = tid & 63;
    int wave = tid >> 6;
    int half = lane >> 5;
    int colq = (lane & 31) * 4;

    const float4 q = *(const float4*)(qk + (size_t)p * 128 + colq);
    float qo = qoff[p];
    int beg = offsets[p], end = offsets[p + 1];
    int n = end - beg;
    int np = (n + 1) >> 1;

    float4 a = {0.f, 0.f, 0.f, 0.f};
    float asum = 0.f;

    int pi = wave;
    for (; pi + 4 < np; pi += 8) {
        int eA = beg + 2 * pi;
        int eB = eA + 8;
        bool hasB1 = (eB + 1 < end);
        int sA0 = ssrc[eA];
        int sA1 = ssrc[eA + 1];
        int sB0 = ssrc[eB];
        int sB1 = hasB1 ? ssrc[eB + 1] : sB0;
        int sA = half ? sA1 : sA0;
        int sB = half ? sB1 : sB0;
        float4 xA = *(const float4*)(nodes + (size_t)sA * 128 + colq);
        float4 xB = *(const float4*)(nodes + (size_t)sB * 128 + colq);
        float dA = xA.x * q.x + xA.y * q.y + xA.z * q.z + xA.w * q.w;
        float dB = xB.x * q.x + xB.y * q.y + xB.z * q.z + xB.w * q.w;
        #pragma unroll
        for (int off = 1; off <= 16; off <<= 1) {
            dA += __shfl_xor(dA, off, 64);
            dB += __shfl_xor(dB, off, 64);
        }
        float attA = (dA + qo) * norm;
        float attB = (dB + qo) * norm;
        if (half && !hasB1) attB = 0.f;
        a.x += attA * xA.x; a.y += attA * xA.y; a.z += attA * xA.z; a.w += attA * xA.w;
        a.x += attB * xB.x; a.y += attB * xB.y; a.z += attB * xB.z; a.w += attB * xB.w;
        asum += attA + attB;
    }
    if (pi < np) {
        int e0 = beg + 2 * pi;
        bool has1 = (e0 + 1 < end);
        int s0 = ssrc[e0];
        int s1 = has1 ? ssrc[e0 + 1] : s0;
        int s = half ? s1 : s0;
        float4 x = *(const float4*)(nodes + (size_t)s * 128 + colq);
        float d = x.x * q.x + x.y * q.y + x.z * q.z + x.w * q.w;
        #pragma unroll
        for (int off = 1; off <= 16; off <<= 1) d += __shfl_xor(d, off, 64);
        float att = (d + qo) * norm;
        if (half && !has1) att = 0.f;
        a.x += att * x.x; a.y += att * x.y; a.z += att * x.z; a.w += att * x.w;
        asum += att;
    }

    a.x += __shfl_xor(a.x, 32, 64);
    a.y += __shfl_xor(a.y, 32, 64);
    a.z += __shfl_xor(a.z, 32, 64);
    a.w += __shfl_xor(a.w, 32, 64);
    asum += __shfl_xor(asum, 32, 64);

    __shared__ float s_acc[4][128];
    __shared__ float s_as[4];
    if (lane < 32) {
        *(float4*)&s_acc[wave][colq] = a;
        if (lane == 0) s_as[wave] = asum;
    }
    __syncthreads();

    if (tid < 128) {
        float v = s_acc[0][tid] + s_acc[1][tid] + s_acc[2][tid] + s_acc[3][tid];
        agg[(size_t)p * 128 + tid] = v;
        if (tid == 0) att_sum[p] = s_as[0] + s_as[1] + s_as[2] + s_as[3];
    }
}

// ---------------------------------------------------------------------------
// K4 v2: fused ws-GEMM + GRU + LN + MLP + residual.
// thread = (particle p_loc = t>>5, column strip j4 = (t&31)*4).
// All weight loads coalesced (lane-consecutive); gates held in registers.
// ---------------------------------------------------------------------------
__global__ __launch_bounds__(256) void gru_fused_v2(
    const float* __restrict__ agg, const float* __restrict__ att_sum,
    const float* __restrict__ ph,
    const float* __restrict__ valW, const float* __restrict__ valb,
    const float* __restrict__ WihT, const float* __restrict__ WhhT,
    const float* __restrict__ bih, const float* __restrict__ bhh,
    const float* __restrict__ lng, const float* __restrict__ lnb,
    const float* __restrict__ W1, const float* __restrict__ b1,
    const float* __restrict__ W2, const float* __restrict__ b2,
    float* __restrict__ out)
{
    __shared__ float s_x[TP][128];   // agg
    __shared__ float s_h[TP][128];
    __shared__ float s_ws[TP][128];
    __shared__ float s_ln[TP][128];
    __shared__ float s_a[TP][64];

    int t = threadIdx.x;
    int pl = t >> 5;          // 0..7
    int jq = t & 31;
    int j4 = jq * 4;
    int p = blockIdx.x * TP + pl;   // 625*8 == 5000, no tail

    float4 h4 = *(const float4*)(ph + (size_t)p * 128 + j4);
    *(float4*)&s_x[pl][j4] = *(const float4*)(agg + (size_t)p * 128 + j4);
    *(float4*)&s_h[pl][j4] = h4;
    float asum = att_sum[p];
    __syncthreads();

    // ---- phase 1: ws = agg @ valW + asum*valb
    float4 ws;
    {
        float4 vb = *(const float4*)(valb + j4);
        ws.x = asum * vb.x; ws.y = asum * vb.y; ws.z = asum * vb.z; ws.w = asum * vb.w;
        #pragma unroll 4
        for (int k = 0; k < 128; k++) {
            float xv = s_x[pl][k];
            float4 w = *(const float4*)(valW + k * 128 + j4);
            ws.x += xv * w.x; ws.y += xv * w.y; ws.z += xv * w.z; ws.w += xv * w.w;
        }
    }
    *(float4*)&s_ws[pl][j4] = ws;
    __syncthreads();

    // ---- phase 2: gi/gh for r,z,n gates (columns j4, 128+j4, 256+j4)
    float4 gir = *(const float4*)(bih + j4);
    float4 giz = *(const float4*)(bih + 128 + j4);
    float4 gin = *(const float4*)(bih + 256 + j4);
    float4 ghr = *(const float4*)(bhh + j4);
    float4 ghz = *(const float4*)(bhh + 128 + j4);
    float4 ghn = *(const float4*)(bhh + 256 + j4);
    #pragma unroll 2
    for (int k = 0; k < 128; k++) {
        float xs = s_ws[pl][k];
        float xh = s_h[pl][k];
        const float* wi = WihT + k * 384;
        const float* wh = WhhT + k * 384;
        float4 a0 = *(const float4*)(wi + j4);
        float4 a1 = *(const float4*)(wi + 128 + j4);
        float4 a2 = *(const float4*)(wi + 256 + j4);
        float4 c0 = *(const float4*)(wh + j4);
        float4 c1 = *(const float4*)(wh + 128 + j4);
        float4 c2 = *(const float4*)(wh + 256 + j4);
        gir.x += xs * a0.x; gir.y += xs * a0.y; gir.z += xs * a0.z; gir.w += xs * a0.w;
        giz.x += xs * a1.x; giz.y += xs * a1.y; giz.z += xs * a1.z; giz.w += xs * a1.w;
        gin.x += xs * a2.x; gin.y += xs * a2.y; gin.z += xs * a2.z; gin.w += xs * a2.w;
        ghr.x += xh * c0.x; ghr.y += xh * c0.y; ghr.z += xh * c0.z; ghr.w += xh * c0.w;
        ghz.x += xh * c1.x; ghz.y += xh * c1.y; ghz.z += xh * c1.z; ghz.w += xh * c1.w;
        ghn.x += xh * c2.x; ghn.y += xh * c2.y; ghn.z += xh * c2.z; ghn.w += xh * c2.w;
    }

    // ---- gates + LayerNorm (in registers; half-wave = one particle row)
    float4 hn;
    {
        float r0 = sigmoid_(gir.x + ghr.x), r1 = sigmoid_(gir.y + ghr.y),
              r2 = sigmoid_(gir.z + ghr.z), r3 = sigmoid_(gir.w + ghr.w);
        float z0 = sigmoid_(giz.x + ghz.x), z1 = sigmoid_(giz.y + ghz.y),
              z2 = sigmoid_(giz.z + ghz.z), z3 = sigmoid_(giz.w + ghz.w);
        float n0 = tanh_(gin.x + r0 * ghn.x), n1 = tanh_(gin.y + r1 * ghn.y),
              n2 = tanh_(gin.z + r2 * ghn.z), n3 = tanh_(gin.w + r3 * ghn.w);
        hn.x = (1.f - z0) * n0 + z0 * h4.x;
        hn.y = (1.f - z1) * n1 + z1 * h4.y;
        hn.z = (1.f - z2) * n2 + z2 * h4.z;
        hn.w = (1.f - z3) * n3 + z3 * h4.w;
    }
    float sum = hn.x + hn.y + hn.z + hn.w;
    float sq  = hn.x * hn.x + hn.y * hn.y + hn.z * hn.z + hn.w * hn.w;
    #pragma unroll
    for (int off = 1; off <= 16; off <<= 1) {
        sum += __shfl_xor(sum, off, 64);
        sq  += __shfl_xor(sq, off, 64);
    }
    float mu = sum * (1.f / 128.f);
    float var = sq * (1.f / 128.f) - mu * mu;
    float rstd = rsqrtf(var + 1e-5f);
    {
        float4 g4 = *(const float4*)(lng + j4);
        float4 b4 = *(const float4*)(lnb + j4);
        float4 ln4;
        ln4.x = (hn.x - mu) * rstd * g4.x + b4.x;
        ln4.y = (hn.y - mu) * rstd * g4.y + b4.y;
        ln4.z = (hn.z - mu) * rstd * g4.z + b4.z;
        ln4.w = (hn.w - mu) * rstd * g4.w + b4.w;
        *(float4*)&s_ln[pl][j4] = ln4;
    }
    __syncthreads();

    // ---- MLP hidden (64): each thread 2 units
    {
        int u2 = jq * 2;
        float a0 = b1[u2], a1 = b1[u2 + 1];
        #pragma unroll 4
        for (int k = 0; k < 128; k++) {
            float lv = s_ln[pl][k];
            float2 w = *(const float2*)(W1 + k * 64 + u2);
            a0 += lv * w.x; a1 += lv * w.y;
        }
        s_a[pl][u2]     = fmaxf(a0, 0.f);
        s_a[pl][u2 + 1] = fmaxf(a1, 0.f);
    }
    __syncthreads();

    // ---- MLP out (128) + residual
    {
        float4 o = *(const float4*)(b2 + j4);
        #pragma unroll 4
        for (int u = 0; u < 64; u++) {
            float av = s_a[pl][u];
            float4 w = *(const float4*)(W2 + u * 128 + j4);
            o.x += av * w.x; o.y += av * w.y; o.z += av * w.z; o.w += av * w.w;
        }
        float4 res;
        res.x = h4.x + o.x; res.y = h4.y + o.y; res.z = h4.z + o.z; res.w = h4.w + o.w;
        *(float4*)(out + (size_t)p * 128 + j4) = res;
    }
}

// ---------------------------------------------------------------------------
extern "C" void kernel_launch(void* const* d_in, const int* in_sizes, int n_in,
                              void* d_out, int out_size, void* d_ws, size_t ws_size,
                              hipStream_t stream) {
    const float* nodes = (const float*)d_in[0];
    const float* ph    = (const float*)d_in[1];
    const float* gr    = (const float*)d_in[2];
    const int*   src   = (const int*)d_in[3];
    const int*   dst   = (const int*)d_in[4];
    const float* keyW  = (const float*)d_in[5];
    const float* keyb  = (const float*)d_in[6];
    const float* valW  = (const float*)d_in[7];
    const float* valb  = (const float*)d_in[8];
    const float* qW    = (const float*)d_in[9];
    const float* qb    = (const float*)d_in[10];
    const float* Wih   = (const float*)d_in[11];
    const float* Whh   = (const float*)d_in[12];
    const float* bih   = (const float*)d_in[13];
    const float* bhh   = (const float*)d_in[14];
    const float* lng   = (const float*)d_in[15];
    const float* lnb   = (const float*)d_in[16];
    const float* W1    = (const float*)d_in[17];
    const float* b1    = (const float*)d_in[18];
    const float* W2    = (const float*)d_in[19];
    const float* b2    = (const float*)d_in[20];
    float* out = (float*)d_out;

    // workspace layout
    float* ws_f      = (float*)d_ws;
    float* qk        = ws_f;                     // 640,000
    float* qoff      = qk + 640000;              // 5,008
    float* agg       = qoff + 5008;              // 640,000
    float* att_sum   = agg + 640000;             // 5,008
    int*   totals    = (int*)(att_sum + 5008);   // 5,008
    int*   offsets   = totals + 5008;            // 5,008
    int*   blockhist = offsets + 5008;           // NBLK*5000
    int*   ssrc      = blockhist + (size_t)NBLK * N_PART;  // 1,000,000
    float* WihT      = (float*)(ssrc + 1000000); // 49,152
    float* WhhT      = WihT + 49152;             // 49,152

    transpose_w_kernel<<<192, 256, 0, stream>>>(Wih, Whh, WihT, WhhT);
    query_qk_kernel<<<N_PART, 128, 0, stream>>>(ph, gr, qW, qb, keyW, keyb, qk, qoff);
    block_hist_kernel<<<NBLK, 256, 0, stream>>>(dst, blockhist);
    colscan_kernel<<<(N_PART + 255) / 256, 256, 0, stream>>>(blockhist, totals);
    scan_kernel<<<1, 256, 0, stream>>>(totals, offsets);
    scatter_sorted_kernel<<<NBLK, 256, 0, stream>>>(src, dst, offsets, blockhist, ssrc);
    edge_agg_kernel<<<N_PART, 256, 0, stream>>>(nodes, qk, qoff, offsets, ssrc, agg, att_sum);
    gru_fused_v2<<<N_PART / TP, 256, 0, stream>>>(
        agg, att_sum, ph, valW, valb, WihT, WhhT, bih, bhh, lng, lnb, W1, b1, W2, b2, out);
}

// Round 4
// 308.347 us; speedup vs baseline: 1.6476x; 1.1313x over previous
//
#include <hip/hip_runtime.h>
#include <math.h>

#define N_NODES 100000
#define N_PART  5000
#define N_EDGES 1000000
#define D_NODE  128
#define D_PART  128
#define D_ATT   20
#define NBLK    128   // counting-sort blocks
#define EPB     ((N_EDGES + NBLK - 1) / NBLK)
#define TPV3    10    // particles per block in gru_fused_v3 (5000 = 500*10)

__device__ __forceinline__ float sigmoid_(float x) { return 1.f / (1.f + __expf(-x)); }
__device__ __forceinline__ float tanh_(float x)    { return 1.f - 2.f / (__expf(2.f * x) + 1.f); }

// ---------------------------------------------------------------------------
// P0: build combined GRU weight matrix Wbig[256][512]:
//   rows 0..127  (agg side k):  cols j<384: Wcomb[k][j] = sum_m valW[k][m]*Wih[j][m]
//                               cols j>=384: 0
//   rows 128..255 (h side k'):  cols j<256:  Whh[j][k']      (r and z gates)
//                               cols 256..383: 0
//                               cols 384..511: Whh[j-128][k'] (n gate)
// Column semantics: [0,128)=r (gi+gh), [128,256)=z (gi+gh), [256,384)=i_n, [384,512)=h_n
// ---------------------------------------------------------------------------
__global__ __launch_bounds__(256) void build_wbig_kernel(
    const float* __restrict__ valW, const float* __restrict__ Wih,
    const float* __restrict__ Whh, float* __restrict__ Wbig)
{
    int idx = blockIdx.x * 256 + threadIdx.x;   // 131072 total
    int k = idx >> 9;
    int j = idx & 511;
    float v = 0.f;
    if (k < 128) {
        if (j < 384) {
            float acc = 0.f;
            #pragma unroll 8
            for (int m = 0; m < 128; m++)
                acc += valW[k * 128 + m] * Wih[j * 128 + m];
            v = acc;
        }
    } else {
        int kp = k - 128;
        if (j < 256)       v = Whh[j * 128 + kp];
        else if (j >= 384) v = Whh[(j - 128) * 128 + kp];
    }
    Wbig[k * 512 + j] = v;
}

// P0b: bvec[c] = sum_m valb[m] * Wih[c][m],  c < 384
__global__ __launch_bounds__(256) void build_bvec_kernel(
    const float* __restrict__ valb, const float* __restrict__ Wih,
    float* __restrict__ bvec)
{
    int c = blockIdx.x * 256 + threadIdx.x;
    if (c < 384) {
        float acc = 0.f;
        #pragma unroll 8
        for (int m = 0; m < 128; m++) acc += valb[m] * Wih[c * 128 + m];
        bvec[c] = acc;
    }
}

// ---------------------------------------------------------------------------
// K1: query = [ph|gr] @ q_W + q_b, fold key_W/key_b:
//     qk[p][j] = sum_a key_W[j][a]*query[p][a];  qoff[p] = key_b . query[p]
// ---------------------------------------------------------------------------
__global__ __launch_bounds__(128) void query_qk_kernel(
    const float* __restrict__ ph, const float* __restrict__ gr,
    const float* __restrict__ qW, const float* __restrict__ qb,
    const float* __restrict__ keyW, const float* __restrict__ keyb,
    float* __restrict__ qk, float* __restrict__ qoff)
{
    int p = blockIdx.x;
    int t = threadIdx.x;
    __shared__ float s_in[256];
    __shared__ float s_q[D_ATT];

    s_in[t]       = ph[p * 128 + t];
    s_in[128 + t] = gr[p * 128 + t];
    __syncthreads();

    if (t < D_ATT) {
        float acc = qb[t];
        #pragma unroll 8
        for (int k = 0; k < 256; k++) acc += s_in[k] * qW[k * D_ATT + t];
        s_q[t] = acc;
    }
    __syncthreads();

    float acc = 0.f;
    #pragma unroll
    for (int a = 0; a < D_ATT; a++) acc += keyW[t * D_ATT + a] * s_q[a];
    qk[p * 128 + t] = acc;

    if (t == 0) {
        float o = 0.f;
        #pragma unroll
        for (int a = 0; a < D_ATT; a++) o += keyb[a] * s_q[a];
        qoff[p] = o;
    }
}

// ---------------------------------------------------------------------------
// K2a: per-block LDS histogram of dst
// ---------------------------------------------------------------------------
__global__ __launch_bounds__(256) void block_hist_kernel(
    const int* __restrict__ dst, int* __restrict__ blockhist)
{
    __shared__ int h[N_PART];
    int b = blockIdx.x;
    for (int i = threadIdx.x; i < N_PART; i += 256) h[i] = 0;
    __syncthreads();
    int beg = b * EPB, end = min(beg + EPB, N_EDGES);
    for (int e = beg + threadIdx.x; e < end; e += 256)
        atomicAdd(&h[dst[e]], 1);
    __syncthreads();
    for (int i = threadIdx.x; i < N_PART; i += 256)
        blockhist[(size_t)b * N_PART + i] = h[i];
}

// ---------------------------------------------------------------------------
// K2b: per-dst column scan over blocks
// ---------------------------------------------------------------------------
__global__ __launch_bounds__(256) void colscan_kernel(
    int* __restrict__ blockhist, int* __restrict__ totals)
{
    int i = blockIdx.x * 256 + threadIdx.x;
    if (i >= N_PART) return;
    int run = 0;
    for (int b = 0; b < NBLK; b++) {
        size_t idx = (size_t)b * N_PART + i;
        int v = blockhist[idx];
        blockhist[idx] = run;
        run += v;
    }
    totals[i] = run;
}

// ---------------------------------------------------------------------------
// K2c: exclusive scan of totals[5000] -> offsets[5001]
// ---------------------------------------------------------------------------
__global__ __launch_bounds__(256) void scan_kernel(
    const int* __restrict__ totals, int* __restrict__ offsets)
{
    __shared__ int ss[256];
    int t = threadIdx.x;
    const int CH = 20;
    int beg = t * CH;
    int end = min(beg + CH, N_PART);
    int lsum = 0;
    for (int i = beg; i < end; i++) lsum += totals[i];
    ss[t] = lsum;
    __syncthreads();
    for (int off = 1; off < 256; off <<= 1) {
        int v = (t >= off) ? ss[t - off] : 0;
        __syncthreads();
        ss[t] += v;
        __syncthreads();
    }
    int base = ss[t] - lsum;
    for (int i = beg; i < end; i++) {
        offsets[i] = base;
        base += totals[i];
    }
    if (t == 0) offsets[N_PART] = N_EDGES;
}

// ---------------------------------------------------------------------------
// K2d: scatter src into dst-sorted order using per-block LDS cursors
// ---------------------------------------------------------------------------
__global__ __launch_bounds__(256) void scatter_sorted_kernel(
    const int* __restrict__ src, const int* __restrict__ dst,
    const int* __restrict__ offsets, const int* __restrict__ blockhist,
    int* __restrict__ ssrc)
{
    __shared__ int cur[N_PART];
    int b = blockIdx.x;
    for (int i = threadIdx.x; i < N_PART; i += 256)
        cur[i] = offsets[i] + blockhist[(size_t)b * N_PART + i];
    __syncthreads();
    int beg = b * EPB, end = min(beg + EPB, N_EDGES);
    for (int e = beg + threadIdx.x; e < end; e += 256) {
        int d = dst[e];
        int pos = atomicAdd(&cur[d], 1);
        ssrc[pos] = src[e];
    }
}

// ---------------------------------------------------------------------------
// K3: per-dst edge accumulation. Half-wave (32 lanes x float4) per edge.
// Main loop: 4 pairs (8 edges) in flight per wave per iteration.
// ---------------------------------------------------------------------------
__global__ __launch_bounds__(256) void edge_agg_kernel(
    const float* __restrict__ nodes, const float* __restrict__ qk,
    const float* __restrict__ qoff,
    const int* __restrict__ offsets, const int* __restrict__ ssrc,
    float* __restrict__ agg, float* __restrict__ att_sum)
{
    const float norm = 0.22360679774997896f;  // 1/sqrt(20)
    int p = blockIdx.x;
    int tid = threadIdx.x;
    int lane = tid & 63;
    int wave = tid >> 6;
    int half = lane >> 5;
    int colq = (lane & 31) * 4;

    const float4 q = *(const float4*)(qk + (size_t)p * 128 + colq);
    float qo = qoff[p];
    int beg = offsets[p], end = offsets[p + 1];
    int n = end - beg;
    int np = (n + 1) >> 1;   // total pairs (last may be partial)
    int npfull = n >> 1;     // pairs with both edges present

    float4 a = {0.f, 0.f, 0.f, 0.f};
    float asum = 0.f;

    int pi = wave;
    // main loop: 4 full pairs pi, pi+4, pi+8, pi+12
    for (; pi + 12 < npfull; pi += 16) {
        int e0 = beg + 2 * pi + half;
        int s0 = ssrc[e0];
        int s1 = ssrc[e0 + 8];
        int s2 = ssrc[e0 + 16];
        int s3 = ssrc[e0 + 24];
        float4 x0 = *(const float4*)(nodes + (size_t)s0 * 128 + colq);
        float4 x1 = *(const float4*)(nodes + (size_t)s1 * 128 + colq);
        float4 x2 = *(const float4*)(nodes + (size_t)s2 * 128 + colq);
        float4 x3 = *(const float4*)(nodes + (size_t)s3 * 128 + colq);
        float d0 = x0.x * q.x + x0.y * q.y + x0.z * q.z + x0.w * q.w;
        float d1 = x1.x * q.x + x1.y * q.y + x1.z * q.z + x1.w * q.w;
        float d2 = x2.x * q.x + x2.y * q.y + x2.z * q.z + x2.w * q.w;
        float d3 = x3.x * q.x + x3.y * q.y + x3.z * q.z + x3.w * q.w;
        #pragma unroll
        for (int off = 1; off <= 16; off <<= 1) {
            d0 += __shfl_xor(d0, off, 64);
            d1 += __shfl_xor(d1, off, 64);
            d2 += __shfl_xor(d2, off, 64);
            d3 += __shfl_xor(d3, off, 64);
        }
        float t0 = (d0 + qo) * norm;
        float t1 = (d1 + qo) * norm;
        float t2 = (d2 + qo) * norm;
        float t3 = (d3 + qo) * norm;
        a.x += t0 * x0.x + t1 * x1.x + t2 * x2.x + t3 * x3.x;
        a.y += t0 * x0.y + t1 * x1.y + t2 * x2.y + t3 * x3.y;
        a.z += t0 * x0.z + t1 * x1.z + t2 * x2.z + t3 * x3.z;
        a.w += t0 * x0.w + t1 * x1.w + t2 * x2.w + t3 * x3.w;
        asum += t0 + t1 + t2 + t3;
    }
    // remainder: guarded single pairs
    for (; pi < np; pi += 4) {
        int e0 = beg + 2 * pi;
        bool has1 = (e0 + 1 < end);
        int s0 = ssrc[e0];
        int s1 = has1 ? ssrc[e0 + 1] : s0;
        int s = half ? s1 : s0;
        float4 x = *(const float4*)(nodes + (size_t)s * 128 + colq);
        float d = x.x * q.x + x.y * q.y + x.z * q.z + x.w * q.w;
        #pragma unroll
        for (int off = 1; off <= 16; off <<= 1) d += __shfl_xor(d, off, 64);
        float att = (d + qo) * norm;
        if (half && !has1) att = 0.f;
        a.x += att * x.x; a.y += att * x.y; a.z += att * x.z; a.w += att * x.w;
        asum += att;
    }

    a.x += __shfl_xor(a.x, 32, 64);
    a.y += __shfl_xor(a.y, 32, 64);
    a.z += __shfl_xor(a.z, 32, 64);
    a.w += __shfl_xor(a.w, 32, 64);
    asum += __shfl_xor(asum, 32, 64);

    __shared__ float s_acc[4][128];
    __shared__ float s_as[4];
    if (lane < 32) {
        *(float4*)&s_acc[wave][colq] = a;
        if (lane == 0) s_as[wave] = asum;
    }
    __syncthreads();

    if (tid < 128) {
        float v = s_acc[0][tid] + s_acc[1][tid] + s_acc[2][tid] + s_acc[3][tid];
        agg[(size_t)p * 128 + tid] = v;
        if (tid == 0) att_sum[p] = s_as[0] + s_as[1] + s_as[2] + s_as[3];
    }
}

// ---------------------------------------------------------------------------
// K4 v3: single K=256 GEMM  G = [agg|h] @ Wbig  (+bias/asum*bvec),
// then gates + LayerNorm + MLP + residual, all in one kernel.
// 256 threads, 10 particles/block, 500 blocks.
// Weight chunks staged in LDS (once per block -> no duplication).
// ---------------------------------------------------------------------------
__global__ __launch_bounds__(256) void gru_fused_v3(
    const float* __restrict__ agg, const float* __restrict__ att_sum,
    const float* __restrict__ ph,
    const float* __restrict__ Wbig, const float* __restrict__ bvec,
    const float* __restrict__ bih, const float* __restrict__ bhh,
    const float* __restrict__ lng, const float* __restrict__ lnb,
    const float* __restrict__ W1, const float* __restrict__ b1,
    const float* __restrict__ W2, const float* __restrict__ b2,
    float* __restrict__ out)
{
    __shared__ float s_in[TPV3][256];    // [agg | h] per particle
    __shared__ float s_w[16][512];       // weight chunk
    __shared__ float s_acc[TPV3][512];   // GEMM outputs
    __shared__ float s_ln[TPV3][128];
    __shared__ float s_hid[TPV3][64];

    int t = threadIdx.x;
    int pbase = blockIdx.x * TPV3;

    // ---- load inputs: 10 particles x 256 floats = 640 float4 jobs
    for (int f = t; f < TPV3 * 64; f += 256) {
        int pl = f >> 6, r = f & 63;
        int c4 = r * 4;
        int p = pbase + pl;
        float4 v;
        if (c4 < 128) v = *(const float4*)(agg + (size_t)p * 128 + c4);
        else          v = *(const float4*)(ph + (size_t)p * 128 + (c4 - 128));
        *(float4*)&s_in[pl][c4] = v;
    }

    // ---- accumulator init: bias + asum * bvec
    int jq = t & 127;        // column quad 0..127
    int j4 = jq * 4;         // absolute column 0..508
    int pg = t >> 7;         // particle group 0/1 -> particles pg*5 .. pg*5+4
    float4 cb, bv;
    if (j4 < 256) {          // r, z: bih + bhh, bvec active
        float4 bi = *(const float4*)(bih + j4);
        float4 bh = *(const float4*)(bhh + j4);
        cb.x = bi.x + bh.x; cb.y = bi.y + bh.y; cb.z = bi.z + bh.z; cb.w = bi.w + bh.w;
        bv = *(const float4*)(bvec + j4);
    } else if (j4 < 384) {   // i_n: bih only, bvec active
        cb = *(const float4*)(bih + j4);
        bv = *(const float4*)(bvec + j4);
    } else {                 // h_n: bhh[j4-128], no bvec
        cb = *(const float4*)(bhh + (j4 - 128));
        bv.x = bv.y = bv.z = bv.w = 0.f;
    }
    float4 acc[5];
    #pragma unroll
    for (int i = 0; i < 5; i++) {
        float as = att_sum[pbase + pg * 5 + i];
        acc[i].x = cb.x + as * bv.x;
        acc[i].y = cb.y + as * bv.y;
        acc[i].z = cb.z + as * bv.z;
        acc[i].w = cb.w + as * bv.w;
    }
    __syncthreads();

    // ---- K-loop: 16 chunks of 16 rows
    for (int kc = 0; kc < 16; kc++) {
        int k0 = kc * 16;
        // stage chunk: 16*512 floats = 2048 float4s, 8 per thread
        #pragma unroll
        for (int f = 0; f < 8; f++) {
            int idx = t + f * 256;          // float4 index
            int row = idx >> 7;
            int c4 = (idx & 127) * 4;
            *(float4*)&s_w[row][c4] = *(const float4*)(Wbig + (size_t)(k0 + row) * 512 + c4);
        }
        __syncthreads();
        #pragma unroll
        for (int kk = 0; kk < 16; kk++) {
            int k = k0 + kk;
            float4 w = *(const float4*)&s_w[kk][j4];
            #pragma unroll
            for (int i = 0; i < 5; i++) {
                float x = s_in[pg * 5 + i][k];
                acc[i].x += x * w.x; acc[i].y += x * w.y;
                acc[i].z += x * w.z; acc[i].w += x * w.w;
            }
        }
        __syncthreads();
    }

    // ---- dump accumulators to LDS
    #pragma unroll
    for (int i = 0; i < 5; i++)
        *(float4*)&s_acc[pg * 5 + i][j4] = acc[i];
    __syncthreads();

    // ---- gates: hn = (1-z)*n + z*h   (320 column-quads)
    for (int idx = t; idx < TPV3 * 32; idx += 256) {
        int pl = idx >> 5, q = idx & 31;
        int c4 = q * 4;
        float4 r4 = *(const float4*)&s_acc[pl][c4];
        float4 z4 = *(const float4*)&s_acc[pl][128 + c4];
        float4 i4 = *(const float4*)&s_acc[pl][256 + c4];
        float4 n4 = *(const float4*)&s_acc[pl][384 + c4];
        float4 h4 = *(const float4*)&s_in[pl][128 + c4];
        float r0 = sigmoid_(r4.x), r1 = sigmoid_(r4.y), r2 = sigmoid_(r4.z), r3 = sigmoid_(r4.w);
        float z0 = sigmoid_(z4.x), z1 = sigmoid_(z4.y), z2 = sigmoid_(z4.z), z3 = sigmoid_(z4.w);
        float n0 = tanh_(i4.x + r0 * n4.x), n1 = tanh_(i4.y + r1 * n4.y);
        float n2 = tanh_(i4.z + r2 * n4.z), n3 = tanh_(i4.w + r3 * n4.w);
        float4 hn;
        hn.x = (1.f - z0) * n0 + z0 * h4.x;
        hn.y = (1.f - z1) * n1 + z1 * h4.y;
        hn.z = (1.f - z2) * n2 + z2 * h4.z;
        hn.w = (1.f - z3) * n3 + z3 * h4.w;
        *(float4*)&s_ln[pl][c4] = hn;
    }
    __syncthreads();

    // ---- LayerNorm per particle (wave w handles particles w, w+4, w+8)
    {
        int wv = t >> 6, l = t & 63;
        for (int pl = wv; pl < TPV3; pl += 4) {
            float v0 = s_ln[pl][l * 2], v1 = s_ln[pl][l * 2 + 1];
            float sum = v0 + v1, sq = v0 * v0 + v1 * v1;
            #pragma unroll
            for (int off = 1; off <= 32; off <<= 1) {
                sum += __shfl_xor(sum, off, 64);
                sq  += __shfl_xor(sq, off, 64);
            }
            float mu = sum * (1.f / 128.f);
            float var = sq * (1.f / 128.f) - mu * mu;
            float rstd = rsqrtf(var + 1e-5f);
            s_ln[pl][l * 2]     = (v0 - mu) * rstd * lng[l * 2] + lnb[l * 2];
            s_ln[pl][l * 2 + 1] = (v1 - mu) * rstd * lng[l * 2 + 1] + lnb[l * 2 + 1];
        }
    }
    __syncthreads();

    // ---- MLP hidden (10*64 = 640 outputs)
    for (int idx = t; idx < TPV3 * 64; idx += 256) {
        int pl = idx >> 6, u = idx & 63;
        float a0 = b1[u];
        #pragma unroll 4
        for (int k = 0; k < 128; k++) a0 += s_ln[pl][k] * W1[k * 64 + u];
        s_hid[pl][u] = fmaxf(a0, 0.f);
    }
    __syncthreads();

    // ---- MLP out + residual (320 column-quads)
    for (int idx = t; idx < TPV3 * 32; idx += 256) {
        int pl = idx >> 5, q = idx & 31;
        int c4 = q * 4;
        float4 o = *(const float4*)(b2 + c4);
        #pragma unroll 4
        for (int u = 0; u < 64; u++) {
            float av = s_hid[pl][u];
            float4 w = *(const float4*)(W2 + u * 128 + c4);
            o.x += av * w.x; o.y += av * w.y; o.z += av * w.z; o.w += av * w.w;
        }
        float4 h4 = *(const float4*)&s_in[pl][128 + c4];
        float4 res;
        res.x = h4.x + o.x; res.y = h4.y + o.y;
        res.z = h4.z + o.z; res.w = h4.w + o.w;
        *(float4*)(out + (size_t)(pbase + pl) * 128 + c4) = res;
    }
}

// ---------------------------------------------------------------------------
extern "C" void kernel_launch(void* const* d_in, const int* in_sizes, int n_in,
                              void* d_out, int out_size, void* d_ws, size_t ws_size,
                              hipStream_t stream) {
    const float* nodes = (const float*)d_in[0];
    const float* ph    = (const float*)d_in[1];
    const float* gr    = (const float*)d_in[2];
    const int*   src   = (const int*)d_in[3];
    const int*   dst   = (const int*)d_in[4];
    const float* keyW  = (const float*)d_in[5];
    const float* keyb  = (const float*)d_in[6];
    const float* valW  = (const float*)d_in[7];
    const float* valb  = (const float*)d_in[8];
    const float* qW    = (const float*)d_in[9];
    const float* qb    = (const float*)d_in[10];
    const float* Wih   = (const float*)d_in[11];
    const float* Whh   = (const float*)d_in[12];
    const float* bih   = (const float*)d_in[13];
    const float* bhh   = (const float*)d_in[14];
    const float* lng   = (const float*)d_in[15];
    const float* lnb   = (const float*)d_in[16];
    const float* W1    = (const float*)d_in[17];
    const float* b1    = (const float*)d_in[18];
    const float* W2    = (const float*)d_in[19];
    const float* b2    = (const float*)d_in[20];
    float* out = (float*)d_out;

    // workspace layout
    float* ws_f      = (float*)d_ws;
    float* qk        = ws_f;                     // 640,000
    float* qoff      = qk + 640000;              // 5,008
    float* agg       = qoff + 5008;              // 640,000
    float* att_sum   = agg + 640000;             // 5,008
    int*   totals    = (int*)(att_sum + 5008);   // 5,008
    int*   offsets   = totals + 5008;            // 5,008
    int*   blockhist = offsets + 5008;           // NBLK*5000
    int*   ssrc      = blockhist + (size_t)NBLK * N_PART;  // 1,000,000
    float* Wbig      = (float*)(ssrc + 1000000); // 131,072
    float* bvec      = Wbig + 131072;            // 384 (+pad)

    build_wbig_kernel<<<512, 256, 0, stream>>>(valW, Wih, Whh, Wbig);
    build_bvec_kernel<<<2, 256, 0, stream>>>(valb, Wih, bvec);
    query_qk_kernel<<<N_PART, 128, 0, stream>>>(ph, gr, qW, qb, keyW, keyb, qk, qoff);
    block_hist_kernel<<<NBLK, 256, 0, stream>>>(dst, blockhist);
    colscan_kernel<<<(N_PART + 255) / 256, 256, 0, stream>>>(blockhist, totals);
    scan_kernel<<<1, 256, 0, stream>>>(totals, offsets);
    scatter_sorted_kernel<<<NBLK, 256, 0, stream>>>(src, dst, offsets, blockhist, ssrc);
    edge_agg_kernel<<<N_PART, 256, 0, stream>>>(nodes, qk, qoff, offsets, ssrc, agg, att_sum);
    gru_fused_v3<<<N_PART / TPV3, 256, 0, stream>>>(
        agg, att_sum, ph, Wbig, bvec, bih, bhh, lng, lnb, W1, b1, W2, b2, out);
}